// Round 5
// baseline (357.506 us; speedup 1.0000x reference)
//
#include <hip/hip_runtime.h>
#include <hip/hip_bf16.h>

namespace {

typedef __attribute__((ext_vector_type(8))) short bf16x8;   // 8 bf16 = 4 VGPRs
typedef __attribute__((ext_vector_type(4))) float f32x4;

constexpr int BATCH = 4;
constexpr int SEQ   = 2048;
constexpr int EMB   = 1024;
constexpr int NH    = 16;
constexpr int HD    = 64;
constexpr int MTOT  = BATCH * SEQ;           // 8192
constexpr int KVW   = 2 * EMB;               // fused K|V row width (2048)
constexpr float LOG2E = 1.44269504088896f;
constexpr float SOFTMAX_C = 16.0f;           // static max substitute (log2 units)

__device__ __forceinline__ unsigned short f2bf(float x) {
    unsigned int u = __float_as_uint(x);
    u += 0x7fffu + ((u >> 16) & 1u);         // round-to-nearest-even
    return (unsigned short)(u >> 16);
}

// pack two floats to bf16 pair (round-half-up)
__device__ __forceinline__ unsigned pack_bf16(float lo, float hi) {
    unsigned ul = __float_as_uint(lo) + 0x8000u;
    unsigned uh = __float_as_uint(hi) + 0x8000u;
    return __builtin_amdgcn_perm(uh, ul, 0x07060302u);   // [uh.hi16 : ul.hi16]
}

// ---------------------------------------------------------------------------
// fp32 -> bf16 for dec (y=0) and enc (y=1) in one launch
// ---------------------------------------------------------------------------
__global__ __launch_bounds__(256)
void conv_bf16(const float* __restrict__ dec, const float* __restrict__ enc,
               unsigned short* __restrict__ decb, unsigned short* __restrict__ encb,
               int n4)
{
    int i = blockIdx.x * 256 + threadIdx.x;
    if (i >= n4) return;
    const float* src = blockIdx.y ? enc : dec;
    unsigned short* dst = blockIdx.y ? encb : decb;
    float4 v = ((const float4*)src)[i];
    ushort4 o;
    o.x = f2bf(v.x); o.y = f2bf(v.y); o.z = f2bf(v.z); o.w = f2bf(v.w);
    ((ushort4*)dst)[i] = o;
}

// ---------------------------------------------------------------------------
// All four weights: W[K][N] fp32 -> Wt[N][K] bf16 (×scale for z=0).
// ---------------------------------------------------------------------------
__global__ __launch_bounds__(256)
void wtrans(const float* __restrict__ W0, const float* __restrict__ W1,
            const float* __restrict__ W2, const float* __restrict__ W3,
            unsigned short* __restrict__ WtBase, float qscale)
{
    __shared__ __align__(16) unsigned short Ts[64][65];
    const int tid = threadIdx.x;
    const int z = blockIdx.z;
    const float* W = (z == 0) ? W0 : (z == 1) ? W1 : (z == 2) ? W2 : W3;
    unsigned short* Wt = WtBase + (size_t)z * EMB * EMB;
    const float scale = (z == 0) ? qscale : 1.0f;
    const int n0 = blockIdx.x * 64, k0 = blockIdx.y * 64;
    #pragma unroll
    for (int i = 0; i < 4; ++i) {
        int id = tid + i * 256;
        int r = id >> 4, q = id & 15;
        float4 v = *(const float4*)&W[(size_t)(k0 + r) * EMB + n0 + q * 4];
        Ts[q * 4 + 0][r] = f2bf(v.x * scale);
        Ts[q * 4 + 1][r] = f2bf(v.y * scale);
        Ts[q * 4 + 2][r] = f2bf(v.z * scale);
        Ts[q * 4 + 3][r] = f2bf(v.w * scale);
    }
    __syncthreads();
    #pragma unroll
    for (int i = 0; i < 4; ++i) {
        int id = tid + i * 256;
        int rn = id >> 4, q = id & 15;
        ushort4 o;
        o.x = Ts[rn][q * 4 + 0]; o.y = Ts[rn][q * 4 + 1];
        o.z = Ts[rn][q * 4 + 2]; o.w = Ts[rn][q * 4 + 3];
        *(ushort4*)&Wt[(size_t)(n0 + rn) * EMB + k0 + q * 4] = o;
    }
}

// ---------------------------------------------------------------------------
// V (cols 1024.. of KVb, row stride KVW) -> Vt[(b*16+h)*64 + d][S] bf16
// ---------------------------------------------------------------------------
__global__ __launch_bounds__(256)
void vtrans(const unsigned short* __restrict__ V, unsigned short* __restrict__ Vt)
{
    __shared__ __align__(16) unsigned short Ts[64][72];
    const int tid = threadIdx.x;
    const int s0 = blockIdx.x * 64;
    const int bh = blockIdx.y, b = bh >> 4, h = bh & 15;
    #pragma unroll
    for (int it = 0; it < 2; ++it) {
        int id = tid + it * 256;
        int r = id >> 3, seg = id & 7;
        uint4 v = *(const uint4*)&V[(size_t)(b * SEQ + s0 + r) * KVW + h * HD + seg * 8];
        const unsigned short* pv = (const unsigned short*)&v;
        #pragma unroll
        for (int j = 0; j < 8; ++j) Ts[seg * 8 + j][r] = pv[j];
    }
    __syncthreads();
    #pragma unroll
    for (int it = 0; it < 2; ++it) {
        int id = tid + it * 256;
        int d = id >> 3, sg = id & 7;
        uint4 w = *(const uint4*)&Ts[d][sg * 8];
        *(uint4*)&Vt[((size_t)bh * HD + d) * SEQ + s0 + sg * 8] = w;
    }
}

// ---------------------------------------------------------------------------
// Shared pipelined GEMM body: C[M,N] = A[M,K] @ Bt[N,K]^T (+bias).
// 128x128 tile, BK=32. VGPR-prefetch: tile k+1 loaded into regs during
// compute of tile k, ds_written after the post-compute barrier (latency
// hidden; no global_load_lds barrier drain).
// ---------------------------------------------------------------------------
template<bool OUT_BF16, bool BIAS>
__device__ __forceinline__
void gemm_body(const unsigned short* __restrict__ A, const unsigned short* __restrict__ Bt,
               const float* __restrict__ bias, void* __restrict__ Cout,
               int m0, int n0, int N, int Kd)
{
    __shared__ __align__(16) unsigned short As[128 * 32];
    __shared__ __align__(16) unsigned short Bs[128 * 32];
    const int tid  = threadIdx.x;
    const int lane = tid & 63, wave = tid >> 6;
    const int g = lane >> 4, c = lane & 15;
    const int wm = (wave & 1) * 64, wn = (wave >> 1) * 64;

    const int r0 = tid >> 2, s = tid & 3;
    const int sg = s ^ ((r0 + (r0 >> 2)) & 3);
    const unsigned short* ga0 = A  + (size_t)(m0 + r0)      * Kd + sg * 8;
    const unsigned short* ga1 = A  + (size_t)(m0 + r0 + 64) * Kd + sg * 8;
    const unsigned short* gb0 = Bt + (size_t)(n0 + r0)      * Kd + sg * 8;
    const unsigned short* gb1 = Bt + (size_t)(n0 + r0 + 64) * Kd + sg * 8;
    unsigned short* la0 = &As[(size_t)tid * 8];
    unsigned short* la1 = &As[(size_t)(256 + tid) * 8];
    unsigned short* lb0 = &Bs[(size_t)tid * 8];
    unsigned short* lb1 = &Bs[(size_t)(256 + tid) * 8];

    const int cs = (c + (c >> 2)) & 3;

    f32x4 acc[4][4];
    #pragma unroll
    for (int i = 0; i < 4; ++i)
        #pragma unroll
        for (int j = 0; j < 4; ++j) acc[i][j] = (f32x4)0.0f;

    // prologue: tile 0 -> LDS; tile 1 -> regs
    uint4 ra0 = *(const uint4*)ga0, ra1 = *(const uint4*)ga1;
    uint4 rb0 = *(const uint4*)gb0, rb1 = *(const uint4*)gb1;
    ga0 += 32; ga1 += 32; gb0 += 32; gb1 += 32;
    *(uint4*)la0 = ra0; *(uint4*)la1 = ra1;
    *(uint4*)lb0 = rb0; *(uint4*)lb1 = rb1;
    ra0 = *(const uint4*)ga0; ra1 = *(const uint4*)ga1;
    rb0 = *(const uint4*)gb0; rb1 = *(const uint4*)gb1;
    ga0 += 32; ga1 += 32; gb0 += 32; gb1 += 32;
    __syncthreads();

    for (int k0 = 0; k0 < Kd; k0 += 32) {
        bf16x8 af[4], bfr[4];
        #pragma unroll
        for (int mt = 0; mt < 4; ++mt)
            af[mt]  = *(const bf16x8*)&As[(wm + mt * 16 + c) * 32 + (g ^ cs) * 8];
        #pragma unroll
        for (int nt = 0; nt < 4; ++nt)
            bfr[nt] = *(const bf16x8*)&Bs[(wn + nt * 16 + c) * 32 + (g ^ cs) * 8];
        #pragma unroll
        for (int mt = 0; mt < 4; ++mt)
            #pragma unroll
            for (int nt = 0; nt < 4; ++nt)
                acc[mt][nt] = __builtin_amdgcn_mfma_f32_16x16x32_bf16(af[mt], bfr[nt], acc[mt][nt], 0, 0, 0);
        __syncthreads();                         // reads of this tile done
        if (k0 + 32 < Kd) {
            *(uint4*)la0 = ra0; *(uint4*)la1 = ra1;   // vmcnt wait lands here
            *(uint4*)lb0 = rb0; *(uint4*)lb1 = rb1;
            if (k0 + 64 < Kd) {
                ra0 = *(const uint4*)ga0; ra1 = *(const uint4*)ga1;
                rb0 = *(const uint4*)gb0; rb1 = *(const uint4*)gb1;
                ga0 += 32; ga1 += 32; gb0 += 32; gb1 += 32;
            }
            __syncthreads();                     // LDS ready for next tile
        }
    }

    #pragma unroll
    for (int mt = 0; mt < 4; ++mt) {
        #pragma unroll
        for (int nt = 0; nt < 4; ++nt) {
            int n = n0 + wn + nt * 16 + c;
            float bv = BIAS ? bias[n] : 0.0f;
            #pragma unroll
            for (int r = 0; r < 4; ++r) {
                int m = m0 + wm + mt * 16 + 4 * g + r;
                float v = acc[mt][nt][r] + bv;
                if (OUT_BF16) ((unsigned short*)Cout)[(size_t)m * N + n] = f2bf(v);
                else          ((float*)Cout)[(size_t)m * N + n] = v;
            }
        }
    }
}

// Fused Q + KV projections: grid.x = 24 n-tiles (0..7 -> Q, 8..23 -> K|V)
__global__ __launch_bounds__(256)
void proj_fused(const unsigned short* __restrict__ decb, const unsigned short* __restrict__ encb,
                const unsigned short* __restrict__ WtBase,
                unsigned short* __restrict__ Qb, unsigned short* __restrict__ KVb)
{
    const int nt = blockIdx.x;
    const int m0 = blockIdx.y * 128;
    if (nt < 8) {
        gemm_body<true, false>(decb, WtBase, nullptr, Qb, m0, nt * 128, EMB, EMB);
    } else {
        gemm_body<true, false>(encb, WtBase + (size_t)EMB * EMB, nullptr, KVb,
                               m0, (nt - 8) * 128, KVW, EMB);
    }
}

// Out projection (fp32 out + bias)
__global__ __launch_bounds__(256)
void proj_out(const unsigned short* __restrict__ Ob, const unsigned short* __restrict__ WoT,
              const float* __restrict__ bo, float* __restrict__ out)
{
    gemm_body<false, true>(Ob, WoT, bo, out, blockIdx.y * 128, blockIdx.x * 128, EMB, EMB);
}

// ---------------------------------------------------------------------------
// MFMA flash attention, S^T formulation, static max folded into MFMA C-init.
// VGPR-prefetch of next K/V tile during compute (latency hidden).
// Block: 128 queries of one (b,h); wave w: 2 bands of 16 queries; 64-key tiles.
// ---------------------------------------------------------------------------
__global__ __launch_bounds__(256, 4)
void attn(const unsigned short* __restrict__ Q, const unsigned short* __restrict__ KV,
          const unsigned short* __restrict__ Vt, unsigned short* __restrict__ O)
{
    __shared__ __align__(16) unsigned short Ks[64 * 64];    // [key][d], seg ^ (row&7)
    __shared__ __align__(16) unsigned short Vs[64 * 64];    // [d][key], seg ^ (row&7)
    __shared__ __align__(16) unsigned short Ps[4][32][72];  // per-wave P [q][key]

    const int tid  = threadIdx.x;
    const int lane = tid & 63, wave = tid >> 6;
    const int g = lane >> 4, c = lane & 15, c7 = c & 7;
    const int bh = blockIdx.y, b = bh >> 4, h = bh & 15;
    const int qw = blockIdx.x * 128 + wave * 32;

    const unsigned short* Qp0 = Q + (size_t)(b * SEQ + qw + c) * EMB + h * HD;
    const unsigned short* Qp1 = Qp0 + (size_t)16 * EMB;
    bf16x8 qb[2][2];
    qb[0][0] = *(const bf16x8*)(Qp0 + g * 8);
    qb[0][1] = *(const bf16x8*)(Qp0 + 32 + g * 8);
    qb[1][0] = *(const bf16x8*)(Qp1 + g * 8);
    qb[1][1] = *(const bf16x8*)(Qp1 + 32 + g * 8);

    const int r0 = tid >> 3, s8 = tid & 7;
    const int sg = s8 ^ (r0 & 7);
    const unsigned short* gK0 = KV + ((size_t)b * SEQ + r0) * KVW + h * HD + sg * 8;
    const unsigned short* gK1 = gK0 + (size_t)32 * KVW;
    const unsigned short* gV0 = Vt + (size_t)bh * HD * SEQ + (size_t)r0 * SEQ + sg * 8;
    const unsigned short* gV1 = gV0 + (size_t)32 * SEQ;
    unsigned short* lK0 = &Ks[(size_t)tid * 8];
    unsigned short* lK1 = &Ks[(size_t)(256 + tid) * 8];
    unsigned short* lV0 = &Vs[(size_t)tid * 8];
    unsigned short* lV1 = &Vs[(size_t)(256 + tid) * 8];

    f32x4 oac[2][4];
    #pragma unroll
    for (int bd = 0; bd < 2; ++bd)
        #pragma unroll
        for (int dt = 0; dt < 4; ++dt) oac[bd][dt] = (f32x4)0.0f;
    float lrun[2] = {0.0f, 0.0f};
    const f32x4 minit = {-SOFTMAX_C, -SOFTMAX_C, -SOFTMAX_C, -SOFTMAX_C};

    // prologue: tile 0 -> LDS; tile 1 -> regs
    uint4 rk0 = *(const uint4*)gK0, rk1 = *(const uint4*)gK1;
    uint4 rv0 = *(const uint4*)gV0, rv1 = *(const uint4*)gV1;
    gK0 += (size_t)64 * KVW; gK1 += (size_t)64 * KVW; gV0 += 64; gV1 += 64;
    *(uint4*)lK0 = rk0; *(uint4*)lK1 = rk1;
    *(uint4*)lV0 = rv0; *(uint4*)lV1 = rv1;
    rk0 = *(const uint4*)gK0; rk1 = *(const uint4*)gK1;
    rv0 = *(const uint4*)gV0; rv1 = *(const uint4*)gV1;
    gK0 += (size_t)64 * KVW; gK1 += (size_t)64 * KVW; gV0 += 64; gV1 += 64;
    __syncthreads();

    constexpr int T = SEQ / 64;
    for (int t = 0; t < T; ++t) {
        // S^T = K Q^T, C-init = -C (softmax shift folded in)
        f32x4 st[2][4];
        #pragma unroll
        for (int kt = 0; kt < 4; ++kt) {
            bf16x8 ka0 = *(const bf16x8*)&Ks[(kt * 16 + c) * 64 + (g ^ c7) * 8];
            bf16x8 ka1 = *(const bf16x8*)&Ks[(kt * 16 + c) * 64 + ((4 + g) ^ c7) * 8];
            #pragma unroll
            for (int bd = 0; bd < 2; ++bd) {
                st[bd][kt] = __builtin_amdgcn_mfma_f32_16x16x32_bf16(ka0, qb[bd][0], minit, 0, 0, 0);
                st[bd][kt] = __builtin_amdgcn_mfma_f32_16x16x32_bf16(ka1, qb[bd][1], st[bd][kt], 0, 0, 0);
            }
        }

        // p = exp2(st); accumulate l; pack to wave-private Ps
        #pragma unroll
        for (int bd = 0; bd < 2; ++bd) {
            float ls = lrun[bd];
            #pragma unroll
            for (int kt = 0; kt < 4; ++kt) {
                float p0 = __builtin_amdgcn_exp2f(st[bd][kt][0]);
                float p1 = __builtin_amdgcn_exp2f(st[bd][kt][1]);
                float p2 = __builtin_amdgcn_exp2f(st[bd][kt][2]);
                float p3 = __builtin_amdgcn_exp2f(st[bd][kt][3]);
                ls += (p0 + p1) + (p2 + p3);
                uint2 u;
                u.x = pack_bf16(p0, p1);
                u.y = pack_bf16(p2, p3);
                *(uint2*)&Ps[wave][bd * 16 + c][kt * 16 + 4 * g] = u;
            }
            lrun[bd] = ls;
        }

        // O += P V
        bf16x8 pa[2][2];
        pa[0][0] = *(const bf16x8*)&Ps[wave][c][g * 8];
        pa[0][1] = *(const bf16x8*)&Ps[wave][c][32 + g * 8];
        pa[1][0] = *(const bf16x8*)&Ps[wave][16 + c][g * 8];
        pa[1][1] = *(const bf16x8*)&Ps[wave][16 + c][32 + g * 8];
        #pragma unroll
        for (int dt = 0; dt < 4; ++dt) {
            bf16x8 vb0 = *(const bf16x8*)&Vs[(dt * 16 + c) * 64 + (g ^ c7) * 8];
            bf16x8 vb1 = *(const bf16x8*)&Vs[(dt * 16 + c) * 64 + ((4 + g) ^ c7) * 8];
            #pragma unroll
            for (int bd = 0; bd < 2; ++bd) {
                oac[bd][dt] = __builtin_amdgcn_mfma_f32_16x16x32_bf16(pa[bd][0], vb0, oac[bd][dt], 0, 0, 0);
                oac[bd][dt] = __builtin_amdgcn_mfma_f32_16x16x32_bf16(pa[bd][1], vb1, oac[bd][dt], 0, 0, 0);
            }
        }

        __syncthreads();                         // K/V reads of tile t done
        if (t + 1 < T) {
            *(uint4*)lK0 = rk0; *(uint4*)lK1 = rk1;   // vmcnt wait (overlapped)
            *(uint4*)lV0 = rv0; *(uint4*)lV1 = rv1;
            if (t + 2 < T) {
                rk0 = *(const uint4*)gK0; rk1 = *(const uint4*)gK1;
                rv0 = *(const uint4*)gV0; rv1 = *(const uint4*)gV1;
                gK0 += (size_t)64 * KVW; gK1 += (size_t)64 * KVW;
                gV0 += 64;               gV1 += 64;
            }
            __syncthreads();                     // LDS ready for tile t+1
        }
    }

    #pragma unroll
    for (int bd = 0; bd < 2; ++bd) {
        float v = lrun[bd];
        v += __shfl_xor(v, 16);
        v += __shfl_xor(v, 32);
        lrun[bd] = v;
    }
    #pragma unroll
    for (int bd = 0; bd < 2; ++bd) {
        unsigned short* Op = O + (size_t)(b * SEQ + qw + bd * 16) * EMB + h * HD;
        #pragma unroll
        for (int r = 0; r < 4; ++r) {
            float linv = 1.0f / __shfl(lrun[bd], 4 * g + r);
            #pragma unroll
            for (int dt = 0; dt < 4; ++dt)
                Op[(size_t)(4 * g + r) * EMB + dt * 16 + c] = f2bf(oac[bd][dt][r] * linv);
        }
    }
}

} // anonymous namespace

extern "C" void kernel_launch(void* const* d_in, const int* in_sizes, int n_in,
                              void* d_out, int out_size, void* d_ws, size_t ws_size,
                              hipStream_t stream)
{
    const float* dec = (const float*)d_in[0];
    const float* enc = (const float*)d_in[1];
    const float* Wq  = (const float*)d_in[2];
    const float* Wk  = (const float*)d_in[3];
    const float* Wv  = (const float*)d_in[4];
    const float* Wo  = (const float*)d_in[5];
    const float* bo  = (const float*)d_in[6];
    float* out = (float*)d_out;

    const size_t BIG = (size_t)MTOT * EMB;     // 8M elems
    const size_t SML = (size_t)EMB * EMB;      // 1M elems
    unsigned short* decb = (unsigned short*)d_ws;
    unsigned short* encb = decb + BIG;
    unsigned short* WqT  = encb + BIG;         // Wq,Wk,Wv,Wo transposed, contiguous
    unsigned short* WoT  = WqT + 3 * SML;
    unsigned short* Qb   = WqT + 4 * SML;
    unsigned short* KVb  = Qb + BIG;           // [8192][2048] fused K|V
    unsigned short* Vtg  = KVb + 2 * BIG;
    unsigned short* Ob   = Vtg + BIG;          // total 120 MB

    dim3 blk(256);

    conv_bf16<<<dim3((unsigned)(BIG / 4 / 256), 2), blk, 0, stream>>>(
        dec, enc, decb, encb, (int)(BIG / 4));

    wtrans<<<dim3(16, 16, 4), blk, 0, stream>>>(Wq, Wk, Wv, Wo, WqT, 0.125f * LOG2E);

    // fused Q | K | V projections: 24 n-tiles x 64 m-tiles = 1536 blocks
    proj_fused<<<dim3(24, MTOT / 128), blk, 0, stream>>>(decb, encb, WqT, Qb, KVb);

    vtrans<<<dim3(SEQ / 64, BATCH * NH), blk, 0, stream>>>(KVb + EMB, Vtg);

    attn<<<dim3(SEQ / 128, BATCH * NH), blk, 0, stream>>>(Qb, KVb, Vtg, Ob);

    proj_out<<<dim3(EMB / 128, MTOT / 128), blk, 0, stream>>>(Ob, WoT, bo, out);
}

// Round 6
// 334.757 us; speedup vs baseline: 1.0680x; 1.0680x over previous
//
#include <hip/hip_runtime.h>
#include <hip/hip_bf16.h>

namespace {

typedef __attribute__((ext_vector_type(8))) short bf16x8;   // 8 bf16 = 4 VGPRs
typedef __attribute__((ext_vector_type(4))) float f32x4;

constexpr int BATCH = 4;
constexpr int SEQ   = 2048;
constexpr int EMB   = 1024;
constexpr int NH    = 16;
constexpr int HD    = 64;
constexpr int MTOT  = BATCH * SEQ;           // 8192
constexpr int KVW   = 2 * EMB;               // fused K|V row width (2048)
constexpr float LOG2E = 1.44269504088896f;
constexpr float SOFTMAX_C = 16.0f;           // static max substitute (log2 units)

__device__ __forceinline__ unsigned short f2bf(float x) {
    unsigned int u = __float_as_uint(x);
    u += 0x7fffu + ((u >> 16) & 1u);         // round-to-nearest-even
    return (unsigned short)(u >> 16);
}

// pack two floats to bf16 pair (round-half-up)
__device__ __forceinline__ unsigned pack_bf16(float lo, float hi) {
    unsigned ul = __float_as_uint(lo) + 0x8000u;
    unsigned uh = __float_as_uint(hi) + 0x8000u;
    return __builtin_amdgcn_perm(uh, ul, 0x07060302u);   // [uh.hi16 : ul.hi16]
}

// async global->LDS, 16B per lane; LDS dest must be wave-uniform base + lane*16
__device__ __forceinline__ void gl_lds16(const void* g, void* l) {
    __builtin_amdgcn_global_load_lds(
        (const __attribute__((address_space(1))) unsigned int*)g,
        (__attribute__((address_space(3))) unsigned int*)l, 16, 0, 0);
}

// ---------------------------------------------------------------------------
// fp32 -> bf16 for dec (y=0) and enc (y=1) in one launch
// ---------------------------------------------------------------------------
__global__ __launch_bounds__(256)
void conv_bf16(const float* __restrict__ dec, const float* __restrict__ enc,
               unsigned short* __restrict__ decb, unsigned short* __restrict__ encb,
               int n4)
{
    int i = blockIdx.x * 256 + threadIdx.x;
    if (i >= n4) return;
    const float* src = blockIdx.y ? enc : dec;
    unsigned short* dst = blockIdx.y ? encb : decb;
    float4 v = ((const float4*)src)[i];
    ushort4 o;
    o.x = f2bf(v.x); o.y = f2bf(v.y); o.z = f2bf(v.z); o.w = f2bf(v.w);
    ((ushort4*)dst)[i] = o;
}

// ---------------------------------------------------------------------------
// All four weights: W[K][N] fp32 -> Wt[N][K] bf16 (×scale for z=0).
// ---------------------------------------------------------------------------
__global__ __launch_bounds__(256)
void wtrans(const float* __restrict__ W0, const float* __restrict__ W1,
            const float* __restrict__ W2, const float* __restrict__ W3,
            unsigned short* __restrict__ WtBase, float qscale)
{
    __shared__ __align__(16) unsigned short Ts[64][65];
    const int tid = threadIdx.x;
    const int z = blockIdx.z;
    const float* W = (z == 0) ? W0 : (z == 1) ? W1 : (z == 2) ? W2 : W3;
    unsigned short* Wt = WtBase + (size_t)z * EMB * EMB;
    const float scale = (z == 0) ? qscale : 1.0f;
    const int n0 = blockIdx.x * 64, k0 = blockIdx.y * 64;
    #pragma unroll
    for (int i = 0; i < 4; ++i) {
        int id = tid + i * 256;
        int r = id >> 4, q = id & 15;
        float4 v = *(const float4*)&W[(size_t)(k0 + r) * EMB + n0 + q * 4];
        Ts[q * 4 + 0][r] = f2bf(v.x * scale);
        Ts[q * 4 + 1][r] = f2bf(v.y * scale);
        Ts[q * 4 + 2][r] = f2bf(v.z * scale);
        Ts[q * 4 + 3][r] = f2bf(v.w * scale);
    }
    __syncthreads();
    #pragma unroll
    for (int i = 0; i < 4; ++i) {
        int id = tid + i * 256;
        int rn = id >> 4, q = id & 15;
        ushort4 o;
        o.x = Ts[rn][q * 4 + 0]; o.y = Ts[rn][q * 4 + 1];
        o.z = Ts[rn][q * 4 + 2]; o.w = Ts[rn][q * 4 + 3];
        *(ushort4*)&Wt[(size_t)(n0 + rn) * EMB + k0 + q * 4] = o;
    }
}

// ---------------------------------------------------------------------------
// V (cols 1024.. of KVb, row stride KVW) -> Vt[(b*16+h)*64 + d][S] bf16
// ---------------------------------------------------------------------------
__global__ __launch_bounds__(256)
void vtrans(const unsigned short* __restrict__ V, unsigned short* __restrict__ Vt)
{
    __shared__ __align__(16) unsigned short Ts[64][72];
    const int tid = threadIdx.x;
    const int s0 = blockIdx.x * 64;
    const int bh = blockIdx.y, b = bh >> 4, h = bh & 15;
    #pragma unroll
    for (int it = 0; it < 2; ++it) {
        int id = tid + it * 256;
        int r = id >> 3, seg = id & 7;
        uint4 v = *(const uint4*)&V[(size_t)(b * SEQ + s0 + r) * KVW + h * HD + seg * 8];
        const unsigned short* pv = (const unsigned short*)&v;
        #pragma unroll
        for (int j = 0; j < 8; ++j) Ts[seg * 8 + j][r] = pv[j];
    }
    __syncthreads();
    #pragma unroll
    for (int it = 0; it < 2; ++it) {
        int id = tid + it * 256;
        int d = id >> 3, sg = id & 7;
        uint4 w = *(const uint4*)&Ts[d][sg * 8];
        *(uint4*)&Vt[((size_t)bh * HD + d) * SEQ + s0 + sg * 8] = w;
    }
}

// ---------------------------------------------------------------------------
// Pipelined GEMM body: C[M,N] = A[M,K] @ Bt[N,K]^T (+bias). 128x128 tile,
// BK=32, DOUBLE-buffered LDS + global_load_lds: loads for tile k+1 issued at
// the top of iteration k (async, no VGPR), ONE barrier per tile whose vmcnt
// drain lands after a full compute phase (latency hidden). Loop unrolled x2
// so buffer indices are compile-time constants.
// ---------------------------------------------------------------------------
template<bool OUT_BF16, bool BIAS>
__device__ __forceinline__
void gemm_body(const unsigned short* __restrict__ A, const unsigned short* __restrict__ Bt,
               const float* __restrict__ bias, void* __restrict__ Cout,
               int m0, int n0, int N, int Kd)
{
    __shared__ __align__(16) unsigned short As[2][128 * 32];
    __shared__ __align__(16) unsigned short Bs[2][128 * 32];
    const int tid  = threadIdx.x;
    const int lane = tid & 63, wave = tid >> 6;
    const int g = lane >> 4, c = lane & 15;
    const int wm = (wave & 1) * 64, wn = (wave >> 1) * 64;

    const int r0 = tid >> 2, s = tid & 3;
    const int sg = s ^ ((r0 + (r0 >> 2)) & 3);
    const unsigned short* ga0 = A  + (size_t)(m0 + r0)      * Kd + sg * 8;
    const unsigned short* ga1 = A  + (size_t)(m0 + r0 + 64) * Kd + sg * 8;
    const unsigned short* gb0 = Bt + (size_t)(n0 + r0)      * Kd + sg * 8;
    const unsigned short* gb1 = Bt + (size_t)(n0 + r0 + 64) * Kd + sg * 8;
    const int lo0 = tid * 8, lo1 = (256 + tid) * 8;

    const int cs = (c + (c >> 2)) & 3;

    f32x4 acc[4][4];
    #pragma unroll
    for (int i = 0; i < 4; ++i)
        #pragma unroll
        for (int j = 0; j < 4; ++j) acc[i][j] = (f32x4)0.0f;

    // prologue: tile 0 -> buf0
    gl_lds16(ga0, &As[0][lo0]); gl_lds16(ga1, &As[0][lo1]);
    gl_lds16(gb0, &Bs[0][lo0]); gl_lds16(gb1, &Bs[0][lo1]);
    ga0 += 32; ga1 += 32; gb0 += 32; gb1 += 32;
    __syncthreads();

    const int KT = Kd / 32;                      // even
    for (int kt = 0; kt < KT; kt += 2) {
        #pragma unroll
        for (int h2 = 0; h2 < 2; ++h2) {         // h2 = buffer parity (constant)
            const int k = kt + h2;
            if (k + 1 < KT) {                    // issue next tile early (async)
                gl_lds16(ga0, &As[h2 ^ 1][lo0]); gl_lds16(ga1, &As[h2 ^ 1][lo1]);
                gl_lds16(gb0, &Bs[h2 ^ 1][lo0]); gl_lds16(gb1, &Bs[h2 ^ 1][lo1]);
                ga0 += 32; ga1 += 32; gb0 += 32; gb1 += 32;
            }
            bf16x8 af[4], bfr[4];
            #pragma unroll
            for (int mt = 0; mt < 4; ++mt)
                af[mt]  = *(const bf16x8*)&As[h2][(wm + mt * 16 + c) * 32 + (g ^ cs) * 8];
            #pragma unroll
            for (int nt = 0; nt < 4; ++nt)
                bfr[nt] = *(const bf16x8*)&Bs[h2][(wn + nt * 16 + c) * 32 + (g ^ cs) * 8];
            #pragma unroll
            for (int mt = 0; mt < 4; ++mt)
                #pragma unroll
                for (int nt = 0; nt < 4; ++nt)
                    acc[mt][nt] = __builtin_amdgcn_mfma_f32_16x16x32_bf16(af[mt], bfr[nt], acc[mt][nt], 0, 0, 0);
            __syncthreads();                     // drain lands post-compute
        }
    }

    #pragma unroll
    for (int mt = 0; mt < 4; ++mt) {
        #pragma unroll
        for (int nt = 0; nt < 4; ++nt) {
            int n = n0 + wn + nt * 16 + c;
            float bv = BIAS ? bias[n] : 0.0f;
            #pragma unroll
            for (int r = 0; r < 4; ++r) {
                int m = m0 + wm + mt * 16 + 4 * g + r;
                float v = acc[mt][nt][r] + bv;
                if (OUT_BF16) ((unsigned short*)Cout)[(size_t)m * N + n] = f2bf(v);
                else          ((float*)Cout)[(size_t)m * N + n] = v;
            }
        }
    }
}

// Fused Q + KV projections: grid.x = 24 n-tiles (0..7 -> Q, 8..23 -> K|V)
__global__ __launch_bounds__(256)
void proj_fused(const unsigned short* __restrict__ decb, const unsigned short* __restrict__ encb,
                const unsigned short* __restrict__ WtBase,
                unsigned short* __restrict__ Qb, unsigned short* __restrict__ KVb)
{
    const int nt = blockIdx.x;
    const int m0 = blockIdx.y * 128;
    if (nt < 8) {
        gemm_body<true, false>(decb, WtBase, nullptr, Qb, m0, nt * 128, EMB, EMB);
    } else {
        gemm_body<true, false>(encb, WtBase + (size_t)EMB * EMB, nullptr, KVb,
                               m0, (nt - 8) * 128, KVW, EMB);
    }
}

// Out projection (fp32 out + bias)
__global__ __launch_bounds__(256)
void proj_out(const unsigned short* __restrict__ Ob, const unsigned short* __restrict__ WoT,
              const float* __restrict__ bo, float* __restrict__ out)
{
    gemm_body<false, true>(Ob, WoT, bo, out, blockIdx.y * 128, blockIdx.x * 128, EMB, EMB);
}

// ---------------------------------------------------------------------------
// MFMA flash attention, S^T formulation, static max folded into MFMA C-init.
// Double-buffered K/V LDS + global_load_lds issued at top of each tile:
// one barrier per tile, drain hidden behind compute.
// Block: 128 queries of one (b,h); wave w: 2 bands of 16 queries; 64-key tiles.
// ---------------------------------------------------------------------------
__global__ __launch_bounds__(256)
void attn(const unsigned short* __restrict__ Q, const unsigned short* __restrict__ KV,
          const unsigned short* __restrict__ Vt, unsigned short* __restrict__ O)
{
    __shared__ __align__(16) unsigned short Ks[2][64 * 64];  // [key][d], seg^(row&7)
    __shared__ __align__(16) unsigned short Vs[2][64 * 64];  // [d][key], seg^(row&7)
    __shared__ __align__(16) unsigned short Ps[4][32][72];   // per-wave P [q][key]

    const int tid  = threadIdx.x;
    const int lane = tid & 63, wave = tid >> 6;
    const int g = lane >> 4, c = lane & 15, c7 = c & 7;
    const int bh = blockIdx.y, b = bh >> 4, h = bh & 15;
    const int qw = blockIdx.x * 128 + wave * 32;

    const unsigned short* Qp0 = Q + (size_t)(b * SEQ + qw + c) * EMB + h * HD;
    const unsigned short* Qp1 = Qp0 + (size_t)16 * EMB;
    bf16x8 qb[2][2];
    qb[0][0] = *(const bf16x8*)(Qp0 + g * 8);
    qb[0][1] = *(const bf16x8*)(Qp0 + 32 + g * 8);
    qb[1][0] = *(const bf16x8*)(Qp1 + g * 8);
    qb[1][1] = *(const bf16x8*)(Qp1 + 32 + g * 8);

    const int r0 = tid >> 3, s8 = tid & 7;
    const int sg = s8 ^ (r0 & 7);
    const unsigned short* gK0 = KV + ((size_t)b * SEQ + r0) * KVW + h * HD + sg * 8;
    const unsigned short* gK1 = gK0 + (size_t)32 * KVW;
    const unsigned short* gV0 = Vt + (size_t)bh * HD * SEQ + (size_t)r0 * SEQ + sg * 8;
    const unsigned short* gV1 = gV0 + (size_t)32 * SEQ;
    const int lo0 = tid * 8, lo1 = (256 + tid) * 8;

    f32x4 oac[2][4];
    #pragma unroll
    for (int bd = 0; bd < 2; ++bd)
        #pragma unroll
        for (int dt = 0; dt < 4; ++dt) oac[bd][dt] = (f32x4)0.0f;
    float lrun[2] = {0.0f, 0.0f};
    const f32x4 minit = {-SOFTMAX_C, -SOFTMAX_C, -SOFTMAX_C, -SOFTMAX_C};

    // prologue: tile 0 -> buf0
    gl_lds16(gK0, &Ks[0][lo0]); gl_lds16(gK1, &Ks[0][lo1]);
    gl_lds16(gV0, &Vs[0][lo0]); gl_lds16(gV1, &Vs[0][lo1]);
    gK0 += (size_t)64 * KVW; gK1 += (size_t)64 * KVW; gV0 += 64; gV1 += 64;
    __syncthreads();

    constexpr int T = SEQ / 64;                  // 32, even
    for (int t = 0; t < T; t += 2) {
        #pragma unroll
        for (int h2 = 0; h2 < 2; ++h2) {         // h2 = buffer parity (constant)
            const int tt = t + h2;
            if (tt + 1 < T) {                    // issue next K/V tile early
                gl_lds16(gK0, &Ks[h2 ^ 1][lo0]); gl_lds16(gK1, &Ks[h2 ^ 1][lo1]);
                gl_lds16(gV0, &Vs[h2 ^ 1][lo0]); gl_lds16(gV1, &Vs[h2 ^ 1][lo1]);
                gK0 += (size_t)64 * KVW; gK1 += (size_t)64 * KVW;
                gV0 += 64;               gV1 += 64;
            }

            // S^T = K Q^T, C-init = -C (softmax shift folded in)
            f32x4 st[2][4];
            #pragma unroll
            for (int kt = 0; kt < 4; ++kt) {
                bf16x8 ka0 = *(const bf16x8*)&Ks[h2][(kt * 16 + c) * 64 + (g ^ c7) * 8];
                bf16x8 ka1 = *(const bf16x8*)&Ks[h2][(kt * 16 + c) * 64 + ((4 + g) ^ c7) * 8];
                #pragma unroll
                for (int bd = 0; bd < 2; ++bd) {
                    st[bd][kt] = __builtin_amdgcn_mfma_f32_16x16x32_bf16(ka0, qb[bd][0], minit, 0, 0, 0);
                    st[bd][kt] = __builtin_amdgcn_mfma_f32_16x16x32_bf16(ka1, qb[bd][1], st[bd][kt], 0, 0, 0);
                }
            }

            // p = exp2(st); accumulate l; pack to wave-private Ps
            #pragma unroll
            for (int bd = 0; bd < 2; ++bd) {
                float ls = lrun[bd];
                #pragma unroll
                for (int kt = 0; kt < 4; ++kt) {
                    float p0 = __builtin_amdgcn_exp2f(st[bd][kt][0]);
                    float p1 = __builtin_amdgcn_exp2f(st[bd][kt][1]);
                    float p2 = __builtin_amdgcn_exp2f(st[bd][kt][2]);
                    float p3 = __builtin_amdgcn_exp2f(st[bd][kt][3]);
                    ls += (p0 + p1) + (p2 + p3);
                    uint2 u;
                    u.x = pack_bf16(p0, p1);
                    u.y = pack_bf16(p2, p3);
                    *(uint2*)&Ps[wave][bd * 16 + c][kt * 16 + 4 * g] = u;
                }
                lrun[bd] = ls;
            }

            // O += P V
            bf16x8 pa[2][2];
            pa[0][0] = *(const bf16x8*)&Ps[wave][c][g * 8];
            pa[0][1] = *(const bf16x8*)&Ps[wave][c][32 + g * 8];
            pa[1][0] = *(const bf16x8*)&Ps[wave][16 + c][g * 8];
            pa[1][1] = *(const bf16x8*)&Ps[wave][16 + c][32 + g * 8];
            #pragma unroll
            for (int dt = 0; dt < 4; ++dt) {
                bf16x8 vb0 = *(const bf16x8*)&Vs[h2][(dt * 16 + c) * 64 + (g ^ c7) * 8];
                bf16x8 vb1 = *(const bf16x8*)&Vs[h2][(dt * 16 + c) * 64 + ((4 + g) ^ c7) * 8];
                #pragma unroll
                for (int bd = 0; bd < 2; ++bd) {
                    oac[bd][dt] = __builtin_amdgcn_mfma_f32_16x16x32_bf16(pa[bd][0], vb0, oac[bd][dt], 0, 0, 0);
                    oac[bd][dt] = __builtin_amdgcn_mfma_f32_16x16x32_bf16(pa[bd][1], vb1, oac[bd][dt], 0, 0, 0);
                }
            }

            __syncthreads();                     // drain (hidden) + buffer handoff
        }
    }

    #pragma unroll
    for (int bd = 0; bd < 2; ++bd) {
        float v = lrun[bd];
        v += __shfl_xor(v, 16);
        v += __shfl_xor(v, 32);
        lrun[bd] = v;
    }
    #pragma unroll
    for (int bd = 0; bd < 2; ++bd) {
        unsigned short* Op = O + (size_t)(b * SEQ + qw + bd * 16) * EMB + h * HD;
        #pragma unroll
        for (int r = 0; r < 4; ++r) {
            float linv = 1.0f / __shfl(lrun[bd], 4 * g + r);
            #pragma unroll
            for (int dt = 0; dt < 4; ++dt)
                Op[(size_t)(4 * g + r) * EMB + dt * 16 + c] = f2bf(oac[bd][dt][r] * linv);
        }
    }
}

} // anonymous namespace

extern "C" void kernel_launch(void* const* d_in, const int* in_sizes, int n_in,
                              void* d_out, int out_size, void* d_ws, size_t ws_size,
                              hipStream_t stream)
{
    const float* dec = (const float*)d_in[0];
    const float* enc = (const float*)d_in[1];
    const float* Wq  = (const float*)d_in[2];
    const float* Wk  = (const float*)d_in[3];
    const float* Wv  = (const float*)d_in[4];
    const float* Wo  = (const float*)d_in[5];
    const float* bo  = (const float*)d_in[6];
    float* out = (float*)d_out;

    const size_t BIG = (size_t)MTOT * EMB;     // 8M elems
    const size_t SML = (size_t)EMB * EMB;      // 1M elems
    unsigned short* decb = (unsigned short*)d_ws;
    unsigned short* encb = decb + BIG;
    unsigned short* WqT  = encb + BIG;         // Wq,Wk,Wv,Wo transposed, contiguous
    unsigned short* WoT  = WqT + 3 * SML;
    unsigned short* Qb   = WqT + 4 * SML;
    unsigned short* KVb  = Qb + BIG;           // [8192][2048] fused K|V
    unsigned short* Vtg  = KVb + 2 * BIG;
    unsigned short* Ob   = Vtg + BIG;          // total 120 MB

    dim3 blk(256);

    conv_bf16<<<dim3((unsigned)(BIG / 4 / 256), 2), blk, 0, stream>>>(
        dec, enc, decb, encb, (int)(BIG / 4));

    wtrans<<<dim3(16, 16, 4), blk, 0, stream>>>(Wq, Wk, Wv, Wo, WqT, 0.125f * LOG2E);

    // fused Q | K | V projections: 24 n-tiles x 64 m-tiles = 1536 blocks
    proj_fused<<<dim3(24, MTOT / 128), blk, 0, stream>>>(decb, encb, WqT, Qb, KVb);

    vtrans<<<dim3(SEQ / 64, BATCH * NH), blk, 0, stream>>>(KVb + EMB, Vtg);

    attn<<<dim3(SEQ / 128, BATCH * NH), blk, 0, stream>>>(Qb, KVb, Vtg, Ob);

    proj_out<<<dim3(EMB / 128, MTOT / 128), blk, 0, stream>>>(Ob, WoT, bo, out);
}